// Round 1
// baseline (878.189 us; speedup 1.0000x reference)
//
#include <hip/hip_runtime.h>
#include <hip/hip_bf16.h>
#include <stdint.h>

// Problem: B=8192, N=32, D_IN=D_HID=D_OUT=512
#define D 512

typedef __attribute__((ext_vector_type(8))) short short8_t;
typedef __attribute__((ext_vector_type(4))) float floatx4;

static __device__ __forceinline__ unsigned short f2bf(float f) {
    union { __hip_bfloat16 h; unsigned short u; } c;
    c.h = __float2bfloat16(f);
    return c.u;
}

// async global -> LDS, 16 B per lane. LDS dest must be wave-uniform base +
// lane*16 (HW constraint); global vaddr may be per-lane arbitrary.
static __device__ __forceinline__ void ld_lds16(const void* g, void* l) {
    __builtin_amdgcn_global_load_lds(
        (const __attribute__((address_space(1))) void*)g,
        (__attribute__((address_space(3))) void*)l, 16, 0, 0);
}

// ---------------------------------------------------------------------------
// Kernel C: transpose + convert the three 512x512 f32 weights to bf16 [n][k]
// (unchanged)
// ---------------------------------------------------------------------------
__global__ void __launch_bounds__(256) prep_weights(
    const float* __restrict__ w1, const float* __restrict__ w2,
    const float* __restrict__ w3,
    unsigned short* __restrict__ w1t, unsigned short* __restrict__ w2t,
    unsigned short* __restrict__ w3t)
{
    int idx = blockIdx.x * 256 + threadIdx.x;   // 0 .. 3*512*512
    int m = idx >> 18;                          // which matrix
    int i = idx & 262143;                       // k*512 + n (coalesced read)
    int k = i >> 9, n = i & 511;
    const float* src = (m == 0) ? w1 : (m == 1) ? w2 : w3;
    unsigned short* dst = (m == 0) ? w1t : (m == 1) ? w2t : w3t;
    dst[n * D + k] = f2bf(src[i]);
}

// ---------------------------------------------------------------------------
// Kernel A v2: h = neigh[262144,512] @ W1 ; pooled[b,:] = relu(max_n h + bias)
//
// BM=128 x BN=256 tile, BK=32, 4 waves (2x2), per-wave 64x128 output
// (acc[4][8]).  Structural change vs v1: A is converted f32->bf16 at STAGING
// (reg-staged, swizzled ds_write_b128) instead of at fragment-read time, and
// LDS is double-buffered with a single barrier per K-step (stage kk+1 issued
// before the MFMA cluster of kk).  Per-K-elem LDS traffic drops from
// ~9 KB/K (f32 A frags + small tile) to ~4.5 KB/K -> MFMA:LDS duty ~53%
// structural ceiling vs 27% before.
//
// Swizzle scheme (involution, chunk = 16 B = 8 bf16, 4 chunks per BK=32 row):
//   LDS pos p of row r holds global chunk p ^ (r&3); reader of chunk q reads
//   pos q ^ (r&3).  Uniform bank spread for reads and writes (checked: slot
//   index (r*4 + q^(r&3)) mod 8 is uniform over any wave's b128 access).
// Pooling: BM=128 rows = 4 batch-groups of 32 neighbors; wave (2M index)
// owns 2 groups; pool raw h then bias+relu once (relu/max commute).
// ---------------------------------------------------------------------------
#define BM 128
#define BN 256
#define BK 32

__global__ void __launch_bounds__(256, 2) mlp_pool_kernel(
    const float* __restrict__ neigh,          // [B*32, 512] f32
    const unsigned short* __restrict__ w1t,   // [512,512] bf16, [n][k]
    const float* __restrict__ bias,           // [512] f32
    unsigned short* __restrict__ pooled)      // [B, 512] bf16
{
    __shared__ __align__(16) short As[2][BM * BK];   // 2 x 8 KB
    __shared__ __align__(16) short Bs[2][BN * BK];   // 2 x 16 KB
    __shared__ float pool_s[4][256];                 // 4 KB

    const int tid  = threadIdx.x;
    const int wave = tid >> 6;
    const int lane = tid & 63;
    const int quad = lane >> 4;
    const int l15  = lane & 15;
    const int mw = (wave >> 1) * 64;    // wave rows mw..mw+63 (2 groups)
    const int nw = (wave & 1) * 128;    // wave cols nw..nw+127

    // XCD-aware swizzle: grid = 4096 = 8 XCDs x 512.  XCD x processes
    // wgid x*512..x*512+511 sequentially -> N-tile pairs (2t,2t+1) of the
    // same A-panel land back-to-back on one XCD (A reread hits L2).
    const int wgid = (blockIdx.x & 7) * 512 + (blockIdx.x >> 3);
    const int m0 = (wgid >> 1) * BM;    // row tile in [B*32]
    const int n0 = (wgid & 1) * BN;     // col tile in D_HID

    // ---- A staging addresses (reg-staged, 2 rounds of 1 chunk/thread) ----
    // round rnd: l = rnd*256 + tid; r = l>>2 (row), pos = l&3 (chunk).
    // rnd advances r by 64 (r&3 invariant) -> constant offsets.
    const int ar = tid >> 2, apos = tid & 3;
    const float* a_src0 = neigh + (size_t)(m0 + ar) * D + apos * 8;
    const int a_off0 = ar * BK + ((apos ^ (ar & 3)) * 8);   // shorts

    // ---- B staging addresses (global_load_lds, 4 rounds/wave) ----
    // ci = wave*256 + rr*64 + lane; r = ci>>2, pos = ci&3.  rr advances r
    // by 16 (r&3 invariant) -> constant offsets.  LDS dest linear in ci
    // (HW constraint); swizzle applied on the GLOBAL source side.
    const int bci = wave * 256 + lane;
    const int br = bci >> 2, bpos = bci & 3;
    const unsigned short* b_src0 =
        w1t + (size_t)(n0 + br) * D + ((bpos ^ (br & 3)) * 8);
    const int bdst_byte0 = bci * 16;    // + rr*1024

    // ---- fragment read offsets (shorts), chunk q=quad at pos q^(r&3) ----
    int aoff[4], boff[8];
#pragma unroll
    for (int mt = 0; mt < 4; ++mt) {
        int r = mw + mt * 16 + l15;
        aoff[mt] = r * BK + ((quad ^ (r & 3)) * 8);
    }
#pragma unroll
    for (int nt = 0; nt < 8; ++nt) {
        int r = nw + nt * 16 + l15;
        boff[nt] = r * BK + ((quad ^ (r & 3)) * 8);
    }

    floatx4 acc[4][8];
#pragma unroll
    for (int i = 0; i < 4; ++i)
#pragma unroll
        for (int j = 0; j < 8; ++j) acc[i][j] = (floatx4){0.f, 0.f, 0.f, 0.f};

    // ---- prologue: stage kk=0 into buffer 0 ----
#pragma unroll
    for (int rr = 0; rr < 4; ++rr)
        ld_lds16(b_src0 + rr * (16 * D),
                 (char*)&Bs[0][0] + bdst_byte0 + rr * 1024);
#pragma unroll
    for (int rnd = 0; rnd < 2; ++rnd) {
        const float4* s = (const float4*)(a_src0 + rnd * (64 * D));
        float4 f0 = s[0], f1 = s[1];
        short8_t v;
        v[0] = (short)f2bf(f0.x); v[1] = (short)f2bf(f0.y);
        v[2] = (short)f2bf(f0.z); v[3] = (short)f2bf(f0.w);
        v[4] = (short)f2bf(f1.x); v[5] = (short)f2bf(f1.y);
        v[6] = (short)f2bf(f1.z); v[7] = (short)f2bf(f1.w);
        *(short8_t*)&As[0][a_off0 + rnd * (64 * BK)] = v;
    }
    __syncthreads();

    // ---- main loop: compute buf[cur], stage kk+1 into buf[cur^1] ----
    int cur = 0;
    for (int kk = 0; kk < 16; ++kk) {
        const int nxt = cur ^ 1;
        float4 f0[2], f1[2];
        if (kk < 15) {
            const int ko = (kk + 1) * BK;   // element offset (f32 A, bf16 B)
            // A global loads first (their waitcnt then leaves B in flight)
#pragma unroll
            for (int rnd = 0; rnd < 2; ++rnd) {
                const float4* s = (const float4*)(a_src0 + rnd * (64 * D) + ko);
                f0[rnd] = s[0];
                f1[rnd] = s[1];
            }
#pragma unroll
            for (int rr = 0; rr < 4; ++rr)
                ld_lds16(b_src0 + rr * (16 * D) + ko,
                         (char*)&Bs[nxt][0] + bdst_byte0 + rr * 1024);
        }

        // compute on buf[cur]
        short8_t af[4], bf[8];
#pragma unroll
        for (int mt = 0; mt < 4; ++mt)
            af[mt] = *(const short8_t*)&As[cur][aoff[mt]];
#pragma unroll
        for (int nt = 0; nt < 8; ++nt)
            bf[nt] = *(const short8_t*)&Bs[cur][boff[nt]];
#pragma unroll
        for (int mt = 0; mt < 4; ++mt)
#pragma unroll
            for (int nt = 0; nt < 8; ++nt)
                acc[mt][nt] = __builtin_amdgcn_mfma_f32_16x16x32_bf16(
                    af[mt], bf[nt], acc[mt][nt], 0, 0, 0);

        if (kk < 15) {
            // convert + swizzled ds_write into buf[nxt]
#pragma unroll
            for (int rnd = 0; rnd < 2; ++rnd) {
                short8_t v;
                v[0] = (short)f2bf(f0[rnd].x); v[1] = (short)f2bf(f0[rnd].y);
                v[2] = (short)f2bf(f0[rnd].z); v[3] = (short)f2bf(f0[rnd].w);
                v[4] = (short)f2bf(f1[rnd].x); v[5] = (short)f2bf(f1[rnd].y);
                v[6] = (short)f2bf(f1[rnd].z); v[7] = (short)f2bf(f1[rnd].w);
                *(short8_t*)&As[nxt][a_off0 + rnd * (64 * BK)] = v;
            }
        }
        __syncthreads();   // drains B gloads + A ds_writes for buf[nxt]
        cur = nxt;
    }

    // ---- max-pool raw h: wave owns groups 2*(wave>>1)+{0,1} ----
    // C/D layout: row = quad*4 + rg (within 16-tile), col = l15.
#pragma unroll
    for (int nt = 0; nt < 8; ++nt) {
        float v0 = -3.4e38f, v1 = -3.4e38f;
#pragma unroll
        for (int rg = 0; rg < 4; ++rg) {
            v0 = fmaxf(v0, fmaxf(acc[0][nt][rg], acc[1][nt][rg]));
            v1 = fmaxf(v1, fmaxf(acc[2][nt][rg], acc[3][nt][rg]));
        }
        v0 = fmaxf(v0, __shfl_xor(v0, 16));
        v0 = fmaxf(v0, __shfl_xor(v0, 32));
        v1 = fmaxf(v1, __shfl_xor(v1, 16));
        v1 = fmaxf(v1, __shfl_xor(v1, 32));
        if (lane < 16) {
            const int g = (wave >> 1) * 2;
            pool_s[g][nw + nt * 16 + l15]     = v0;
            pool_s[g + 1][nw + nt * 16 + l15] = v1;
        }
    }
    __syncthreads();
#pragma unroll
    for (int it = 0; it < 4; ++it) {
        int i = it * 256 + tid;
        int g = i >> 8, col = i & 255;
        float v = fmaxf(pool_s[g][col] + bias[n0 + col], 0.0f);
        pooled[(size_t)((m0 >> 5) + g) * D + n0 + col] = f2bf(v);
    }
}

// ---------------------------------------------------------------------------
// Kernel B: out = relu(pooled @ W2 + self @ W3), M=8192, N=512, K=512 (x2)
// Virtual K-loop of 16 blocks: kk<8 -> pooled/W2t (bf16), kk>=8 -> self/W3t.
// (unchanged — not the measured bottleneck)
// ---------------------------------------------------------------------------
__global__ void __launch_bounds__(256) out_gemm_kernel(
    const unsigned short* __restrict__ pooled, // [B,512] bf16
    const float* __restrict__ selfv,           // [B,512] f32
    const unsigned short* __restrict__ w2t,    // neigh_w^T bf16 [n][k]
    const unsigned short* __restrict__ w3t,    // self_w^T bf16 [n][k]
    float* __restrict__ out)                   // [B,512] f32
{
    __shared__ __align__(16) short As2[128 * 64];
    __shared__ __align__(16) short Bs2[128 * 64];

    const int tid  = threadIdx.x;
    const int wave = tid >> 6;
    const int lane = tid & 63;
    const int quad = lane >> 4;
    const int l15  = lane & 15;
    const int mw = (wave >> 1) * 64;
    const int nw = (wave & 1) * 64;

    const int m0 = (blockIdx.x >> 2) * 128;
    const int n0 = (blockIdx.x & 3) * 128;

    floatx4 acc[4][4];
#pragma unroll
    for (int i = 0; i < 4; ++i)
#pragma unroll
        for (int j = 0; j < 4; ++j) acc[i][j] = (floatx4){0.f, 0.f, 0.f, 0.f};

    for (int kk = 0; kk < 16; ++kk) {
        const int k0 = (kk & 7) * 64;
        __syncthreads();
        if (kk < 8) {
#pragma unroll
            for (int rnd = 0; rnd < 4; ++rnd) {
                int l = rnd * 256 + tid;
                int r = l >> 3, g = l & 7;
                short8_t v = *reinterpret_cast<const short8_t*>(
                    pooled + (size_t)(m0 + r) * D + k0 + g * 8);
                *reinterpret_cast<short8_t*>(&As2[r * 64 + ((g ^ (r & 7)) * 8)]) = v;
            }
#pragma unroll
            for (int rnd = 0; rnd < 4; ++rnd) {
                int l = rnd * 256 + tid;
                int r = l >> 3, g = l & 7;
                short8_t v = *reinterpret_cast<const short8_t*>(
                    w2t + (size_t)(n0 + r) * D + k0 + g * 8);
                *reinterpret_cast<short8_t*>(&Bs2[r * 64 + ((g ^ (r & 7)) * 8)]) = v;
            }
        } else {
#pragma unroll
            for (int rnd = 0; rnd < 4; ++rnd) {
                int l = rnd * 256 + tid;
                int r = l >> 3, g = l & 7;
                const float4* src = reinterpret_cast<const float4*>(
                    selfv + (size_t)(m0 + r) * D + k0 + g * 8);
                float4 f0 = src[0];
                float4 f1 = src[1];
                short8_t v;
                v[0] = (short)f2bf(f0.x); v[1] = (short)f2bf(f0.y);
                v[2] = (short)f2bf(f0.z); v[3] = (short)f2bf(f0.w);
                v[4] = (short)f2bf(f1.x); v[5] = (short)f2bf(f1.y);
                v[6] = (short)f2bf(f1.z); v[7] = (short)f2bf(f1.w);
                *reinterpret_cast<short8_t*>(&As2[r * 64 + ((g ^ (r & 7)) * 8)]) = v;
            }
#pragma unroll
            for (int rnd = 0; rnd < 4; ++rnd) {
                int l = rnd * 256 + tid;
                int r = l >> 3, g = l & 7;
                short8_t v = *reinterpret_cast<const short8_t*>(
                    w3t + (size_t)(n0 + r) * D + k0 + g * 8);
                *reinterpret_cast<short8_t*>(&Bs2[r * 64 + ((g ^ (r & 7)) * 8)]) = v;
            }
        }
        __syncthreads();
#pragma unroll
        for (int s = 0; s < 2; ++s) {
            short8_t af[4], bfr[4];
#pragma unroll
            for (int mt = 0; mt < 4; ++mt) {
                int r = mw + mt * 16 + l15;
                int c = (s * 4 + quad) ^ (r & 7);
                af[mt] = *reinterpret_cast<const short8_t*>(&As2[r * 64 + c * 8]);
            }
#pragma unroll
            for (int nt = 0; nt < 4; ++nt) {
                int r = nw + nt * 16 + l15;
                int c = (s * 4 + quad) ^ (r & 7);
                bfr[nt] = *reinterpret_cast<const short8_t*>(&Bs2[r * 64 + c * 8]);
            }
#pragma unroll
            for (int mt = 0; mt < 4; ++mt)
#pragma unroll
                for (int nt = 0; nt < 4; ++nt)
                    acc[mt][nt] = __builtin_amdgcn_mfma_f32_16x16x32_bf16(
                        af[mt], bfr[nt], acc[mt][nt], 0, 0, 0);
        }
    }

#pragma unroll
    for (int mt = 0; mt < 4; ++mt)
#pragma unroll
        for (int nt = 0; nt < 4; ++nt)
#pragma unroll
            for (int rg = 0; rg < 4; ++rg) {
                int row = m0 + mw + mt * 16 + quad * 4 + rg;
                int col = n0 + nw + nt * 16 + l15;
                out[(size_t)row * D + col] = fmaxf(acc[mt][nt][rg], 0.0f);
            }
}

// ---------------------------------------------------------------------------
extern "C" void kernel_launch(void* const* d_in, const int* in_sizes, int n_in,
                              void* d_out, int out_size, void* d_ws, size_t ws_size,
                              hipStream_t stream) {
    const float* selfv = (const float*)d_in[0];   // [8192,512]
    const float* neigh = (const float*)d_in[1];   // [8192,32,512]
    const float* w1    = (const float*)d_in[2];   // mlp_w [512,512]
    const float* b1    = (const float*)d_in[3];   // mlp_b [512]
    const float* w2    = (const float*)d_in[4];   // neigh_w [512,512]
    const float* w3    = (const float*)d_in[5];   // self_w [512,512]
    float* out = (float*)d_out;

    // ws layout: pooled bf16 [8192*512] (8 MB) | w1t | w2t | w3t (512 KB each)
    unsigned short* pooled = (unsigned short*)d_ws;
    unsigned short* w1t = (unsigned short*)((char*)d_ws + 8388608);
    unsigned short* w2t = w1t + 262144;
    unsigned short* w3t = w2t + 262144;

    prep_weights<<<3072, 256, 0, stream>>>(w1, w2, w3, w1t, w2t, w3t);
    // M-tiles = 262144/128 = 2048, N-tiles = 2 -> 4096 blocks (swizzle needs
    // grid % 8 == 0 and exactly 4096 for the bijection)
    mlp_pool_kernel<<<4096, 256, 0, stream>>>(neigh, w1t, b1, pooled);
    // M-tiles = 8192/128 = 64, N-tiles = 4
    out_gemm_kernel<<<256, 256, 0, stream>>>(pooled, selfv, w2t, w3t, out);
}